// Round 2
// baseline (355.979 us; speedup 1.0000x reference)
//
#include <hip/hip_runtime.h>

#define LN2F      0.69314718055994530942f
#define LOG2EF    1.44269504088896340736f

__device__ __forceinline__ float laexp_terms(float x, float t, float& s_hi, float& s_lg) {
    // accumulate logaddexp(x, t) = hi + ln2*log2(1 + exp(lo-hi))
    float hi = fmaxf(x, t);
    float lo = fminf(x, t);
    float e  = __builtin_amdgcn_exp2f((lo - hi) * LOG2EF);   // exp(lo-hi)
    s_hi += hi;
    s_lg += __builtin_amdgcn_logf(1.0f + e);                  // log2(1+e)
    return hi;
}

// One wave (64 lanes) per row. M=1024 fp32 = 256 float4 = exactly 4 float4/lane.
__global__ __launch_bounds__(256) void tuplemax_loss_1024(
    const float* __restrict__ logits,
    const int*   __restrict__ true_idx,
    float*       __restrict__ out,
    int n)
{
    const int lane            = threadIdx.x & 63;
    const int wid             = threadIdx.x >> 6;
    const int gwave           = blockIdx.x * 4 + wid;
    const int nwaves          = gridDim.x * 4;

    float acc = 0.0f;   // lane-0 accumulated loss across this wave's rows

    for (int row = gwave; row < n; row += nwaves) {
        const int   tidx = true_idx[row];
        const float t    = logits[(size_t)row * 1024 + tidx];   // same addr all lanes
        const float4* rowp = (const float4*)(logits + (size_t)row * 1024) + lane;

        // issue all 4 16B loads before any dependent math
        float4 v0 = rowp[0];
        float4 v1 = rowp[64];
        float4 v2 = rowp[128];
        float4 v3 = rowp[192];

        float s_hi = 0.0f, s_lg = 0.0f;
        #pragma unroll
        for (int j = 0; j < 4; ++j) laexp_terms((&v0.x)[j], t, s_hi, s_lg);
        #pragma unroll
        for (int j = 0; j < 4; ++j) laexp_terms((&v1.x)[j], t, s_hi, s_lg);
        #pragma unroll
        for (int j = 0; j < 4; ++j) laexp_terms((&v2.x)[j], t, s_hi, s_lg);
        #pragma unroll
        for (int j = 0; j < 4; ++j) laexp_terms((&v3.x)[j], t, s_hi, s_lg);

        float s = fmaf(s_lg, LN2F, s_hi);   // lane-partial Σ logaddexp

        #pragma unroll
        for (int off = 32; off >= 1; off >>= 1)
            s += __shfl_xor(s, off, 64);

        if (lane == 0) {
            float logsum = s - (t + LN2F);          // drop j==true term
            acc += logsum * (1.0f / 1023.0f) - t;   // /(m-1) - t
        }
    }

    __shared__ float partial[4];
    if (lane == 0) partial[wid] = acc;
    __syncthreads();
    if (threadIdx.x == 0) {
        float s = partial[0] + partial[1] + partial[2] + partial[3];
        atomicAdd(out, s * (1.0f / (float)n));
    }
}

// Generic fallback (any m divisible by 4).
__global__ __launch_bounds__(256) void tuplemax_loss_generic(
    const float* __restrict__ logits,
    const int*   __restrict__ true_idx,
    float*       __restrict__ out,
    int n, int m)
{
    const int lane   = threadIdx.x & 63;
    const int wid    = threadIdx.x >> 6;
    const int gwave  = blockIdx.x * 4 + wid;
    const int nwaves = gridDim.x * 4;
    const int m4     = m >> 2;

    float acc = 0.0f;

    for (int row = gwave; row < n; row += nwaves) {
        const int   tidx = true_idx[row];
        const float t    = logits[(size_t)row * m + tidx];
        const float4* rowp = (const float4*)(logits + (size_t)row * m);

        float s_hi = 0.0f, s_lg = 0.0f;
        for (int k4 = lane; k4 < m4; k4 += 64) {
            float4 v = rowp[k4];
            #pragma unroll
            for (int j = 0; j < 4; ++j) laexp_terms((&v.x)[j], t, s_hi, s_lg);
        }
        float s = fmaf(s_lg, LN2F, s_hi);

        #pragma unroll
        for (int off = 32; off >= 1; off >>= 1)
            s += __shfl_xor(s, off, 64);

        if (lane == 0) {
            float logsum = s - (t + LN2F);
            acc += logsum / (float)(m - 1) - t;
        }
    }

    __shared__ float partial[4];
    if (lane == 0) partial[wid] = acc;
    __syncthreads();
    if (threadIdx.x == 0) {
        float s = partial[0] + partial[1] + partial[2] + partial[3];
        atomicAdd(out, s * (1.0f / (float)n));
    }
}

extern "C" void kernel_launch(void* const* d_in, const int* in_sizes, int n_in,
                              void* d_out, int out_size, void* d_ws, size_t ws_size,
                              hipStream_t stream) {
    const float* logits = (const float*)d_in[0];
    const int*   tidx   = (const int*)d_in[1];
    float*       out    = (float*)d_out;

    const int n = in_sizes[1];               // 65536 rows
    const int m = in_sizes[0] / n;           // 1024 classes

    hipMemsetAsync(out, 0, sizeof(float), stream);   // d_out is poisoned 0xAA

    const int block = 256;                   // 4 waves/block
    const int grid  = 2048;                  // 8 rows per wave, grid-stride
    if (m == 1024) {
        tuplemax_loss_1024<<<grid, block, 0, stream>>>(logits, tidx, out, n);
    } else {
        tuplemax_loss_generic<<<grid, block, 0, stream>>>(logits, tidx, out, n, m);
    }
}

// Round 4
// 354.409 us; speedup vs baseline: 1.0044x; 1.0044x over previous
//
#include <hip/hip_runtime.h>

#define LN2F   0.69314718055994530942f
#define LOG2EF 1.44269504088896340736f

__device__ __forceinline__ void laexp1(float x, float t, float& s_hi, float& s_lg) {
    // logaddexp(x, t) = hi + ln2 * log2(1 + exp(lo - hi))
    float hi = fmaxf(x, t);
    float lo = fminf(x, t);
    s_hi += hi;
    s_lg += __builtin_amdgcn_logf(1.0f + __builtin_amdgcn_exp2f((lo - hi) * LOG2EF));
}

__device__ __forceinline__ void laexp16(const float4& q0, const float4& q1,
                                        const float4& q2, const float4& q3,
                                        float t, float& s_hi, float& s_lg) {
    laexp1(q0.x, t, s_hi, s_lg); laexp1(q0.y, t, s_hi, s_lg);
    laexp1(q0.z, t, s_hi, s_lg); laexp1(q0.w, t, s_hi, s_lg);
    laexp1(q1.x, t, s_hi, s_lg); laexp1(q1.y, t, s_hi, s_lg);
    laexp1(q1.z, t, s_hi, s_lg); laexp1(q1.w, t, s_hi, s_lg);
    laexp1(q2.x, t, s_hi, s_lg); laexp1(q2.y, t, s_hi, s_lg);
    laexp1(q2.z, t, s_hi, s_lg); laexp1(q2.w, t, s_hi, s_lg);
    laexp1(q3.x, t, s_hi, s_lg); laexp1(q3.y, t, s_hi, s_lg);
    laexp1(q3.z, t, s_hi, s_lg); laexp1(q3.w, t, s_hi, s_lg);
}

// One wave per 8 CONTIGUOUS rows. M=1024 fp32 = 256 float4 = 4 float4/lane/row.
// All idx loads + all t loads hoisted; row stream double-buffered in registers;
// reductions deferred to one butterfly per wave (loss is affine in s_r, t_r).
__global__ __launch_bounds__(256) void tuplemax_loss_1024(
    const float* __restrict__ logits,
    const int*   __restrict__ true_idx,
    float*       __restrict__ out,
    int n)
{
    const int lane = threadIdx.x & 63;
    const int wid  = threadIdx.x >> 6;
    const int w    = blockIdx.x * 4 + wid;       // wave id
    const int row0 = w * 8;                      // 8 contiguous rows per wave

    const float* base = logits + (size_t)row0 * 1024;

#define LOADR(Q0, Q1, Q2, Q3, K) do {                                   \
        const float4* rp = (const float4*)(base + ((size_t)(K) << 10)) + lane; \
        Q0 = rp[0]; Q1 = rp[64]; Q2 = rp[128]; Q3 = rp[192];            \
    } while (0)

    // 2 rows of stream loads in flight before anything dependent
    float4 a0, a1, a2, a3, b0, b1, b2, b3;
    LOADR(a0, a1, a2, a3, 0);
    LOADR(b0, b1, b2, b3, 1);

    // all 8 indices: two broadcast 16B loads (row0*4B is 32B-aligned)
    const int4 ia = *(const int4*)(true_idx + row0);
    const int4 ib = *(const int4*)(true_idx + row0 + 4);

    // all 8 true-logit loads, independent of each other
    float tv[8];
    tv[0] = base[(0 << 10) + ia.x];
    tv[1] = base[(1 << 10) + ia.y];
    tv[2] = base[(2 << 10) + ia.z];
    tv[3] = base[(3 << 10) + ia.w];
    tv[4] = base[(4 << 10) + ib.x];
    tv[5] = base[(5 << 10) + ib.y];
    tv[6] = base[(6 << 10) + ib.z];
    tv[7] = base[(7 << 10) + ib.w];

    float s_hi = 0.0f, s_lg = 0.0f, tsum = 0.0f;

    #pragma unroll
    for (int k = 0; k < 8; k += 2) {
        tsum += tv[k] + tv[k + 1];               // uniform across lanes
        laexp16(a0, a1, a2, a3, tv[k], s_hi, s_lg);
        if (k + 2 < 8) LOADR(a0, a1, a2, a3, k + 2);
        laexp16(b0, b1, b2, b3, tv[k + 1], s_hi, s_lg);
        if (k + 3 < 8) LOADR(b0, b1, b2, b3, k + 3);
    }
#undef LOADR

    // lane-partial of Sigma_r s_r; one butterfly per wave
    float S = fmaf(s_lg, LN2F, s_hi);
    #pragma unroll
    for (int off = 32; off >= 1; off >>= 1)
        S += __shfl_xor(S, off, 64);

    __shared__ float partial[4];
    if (lane == 0) {
        // Sigma_r loss_r = S/1023 - tsum*(1024/1023) - 8*ln2/1023
        partial[wid] = S * (1.0f / 1023.0f)
                     - tsum * (1024.0f / 1023.0f)
                     - 8.0f * LN2F * (1.0f / 1023.0f);
    }
    __syncthreads();
    if (threadIdx.x == 0) {
        float s = partial[0] + partial[1] + partial[2] + partial[3];
        atomicAdd(out, s * (1.0f / (float)n));
    }
}

// Generic fallback (any m divisible by 4), grid-stride, one wave per row.
__global__ __launch_bounds__(256) void tuplemax_loss_generic(
    const float* __restrict__ logits,
    const int*   __restrict__ true_idx,
    float*       __restrict__ out,
    int n, int m)
{
    const int lane   = threadIdx.x & 63;
    const int wid    = threadIdx.x >> 6;
    const int gwave  = blockIdx.x * 4 + wid;
    const int nwaves = gridDim.x * 4;
    const int m4     = m >> 2;

    float acc = 0.0f;
    for (int row = gwave; row < n; row += nwaves) {
        const int   tidx = true_idx[row];
        const float t    = logits[(size_t)row * m + tidx];
        const float4* rowp = (const float4*)(logits + (size_t)row * m);

        float s_hi = 0.0f, s_lg = 0.0f;
        for (int k4 = lane; k4 < m4; k4 += 64) {
            float4 v = rowp[k4];
            laexp1(v.x, t, s_hi, s_lg); laexp1(v.y, t, s_hi, s_lg);
            laexp1(v.z, t, s_hi, s_lg); laexp1(v.w, t, s_hi, s_lg);
        }
        float s = fmaf(s_lg, LN2F, s_hi);
        #pragma unroll
        for (int off = 32; off >= 1; off >>= 1)
            s += __shfl_xor(s, off, 64);
        if (lane == 0) {
            float logsum = s - (t + LN2F);
            acc += logsum / (float)(m - 1) - t;
        }
    }

    __shared__ float partial[4];
    if (lane == 0) partial[wid] = acc;
    __syncthreads();
    if (threadIdx.x == 0) {
        float s = partial[0] + partial[1] + partial[2] + partial[3];
        atomicAdd(out, s * (1.0f / (float)n));
    }
}

extern "C" void kernel_launch(void* const* d_in, const int* in_sizes, int n_in,
                              void* d_out, int out_size, void* d_ws, size_t ws_size,
                              hipStream_t stream) {
    const float* logits = (const float*)d_in[0];
    const int*   tidx   = (const int*)d_in[1];
    float*       out    = (float*)d_out;

    const int n = in_sizes[1];               // 65536 rows
    const int m = in_sizes[0] / n;           // 1024 classes

    hipMemsetAsync(out, 0, sizeof(float), stream);   // d_out is poisoned 0xAA

    if (m == 1024 && (n % 32) == 0) {
        const int grid = n / 32;             // 4 waves/block x 8 rows/wave
        tuplemax_loss_1024<<<grid, 256, 0, stream>>>(logits, tidx, out, n);
    } else {
        tuplemax_loss_generic<<<2048, 256, 0, stream>>>(logits, tidx, out, n, m);
    }
}